// Round 2
// baseline (1826.758 us; speedup 1.0000x reference)
//
#include <hip/hip_runtime.h>

// LSTM: SEQ=512, B=64, IN=256, H=512, fp32 in/out; bf16 MFMA compute.
//
// NEW topology: 8 groups (8 batch rows each) x 16 H-slice blocks = 128 blocks.
// group = blockIdx & 7  ==> under round-robin dispatch all 16 blocks of a
// group land on ONE XCD and exchange h through the SHARED per-XCD L2
// (sc0-only stores/loads, ~200cy RT) instead of the MALL (~2+us RT).
//
// Self-validating protocol (placement is formally undefined):
//   warmup (t<8): dual-store (fast sc0 + slow sc0sc1), poll fast w/ 128-iter
//     cap, fall back to slow poll; any fallback sets warm_fail.
//   consensus at t==8: device-wide counter + any_slow flag (one-time ~us).
//   t>=8 fast mode: sc0-only stores + fast poll (no MALL ops anywhere in the
//     loop => poll's vmcnt(0) never waits a MALL store-ack).
//   t>=8 slow mode: sc0sc1-only (== round-1 protocol, proven correct).
// Chunks are self-certifying: [4 x bf16 | tag=t+1 | pad] per 16B single-instr
// store => tag travels with data, no flags, no producer drain.
// x prefetch: parity register pairs (issued 1 full iteration before use).
// MFMA M-dim padded (8 of 16 rows used; garbage rows zeroed once, never read).

#define T_STEPS 512
#define BATCH   64
#define IN_D    256
#define HID     512
#define NGROUP  8
#define NSLICE  16
#define BLK_B   8
#define BLK_H   32
#define THREADS 512
#define NBLK    (NGROUP * NSLICE)
#define CH_ROW  128                                  // 16B chunks per row: 512/4
#define SLOT_BYTES (NGROUP * BLK_B * CH_ROW * 16)    // 64*128*16 = 131072
#define WARMUP   8
#define FAST_CAP 128

using short8  = __attribute__((ext_vector_type(8))) short;
using int4v   = __attribute__((ext_vector_type(4))) int;
using float4v = __attribute__((ext_vector_type(4))) float;

#define FRAG_ADDR(f) (((f) << 4) + (((f) >> 4) << 4))   // 16B frag + 16B pad / 16 frags

__device__ __forceinline__ unsigned short f2bf(float f) {
    union { float f; unsigned int i; } v; v.f = f;
    unsigned int r = v.i + 0x7fff + ((v.i >> 16) & 1);
    return (unsigned short)(r >> 16);
}
__device__ __forceinline__ short8 pack8(float4 a, float4 b) {
    short8 s;
    s[0]=(short)f2bf(a.x); s[1]=(short)f2bf(a.y); s[2]=(short)f2bf(a.z); s[3]=(short)f2bf(a.w);
    s[4]=(short)f2bf(b.x); s[5]=(short)f2bf(b.y); s[6]=(short)f2bf(b.z); s[7]=(short)f2bf(b.w);
    return s;
}
__device__ __forceinline__ float sigm(float v) { return 1.0f / (1.0f + __expf(-v)); }
__device__ __forceinline__ float tanh_(float v) { return 2.0f / (1.0f + __expf(-2.0f * v)) - 1.0f; }

// LDS-visibility barrier WITHOUT the vmcnt(0) drain of __syncthreads.
__device__ __forceinline__ void lds_barrier() {
    asm volatile("s_waitcnt lgkmcnt(0)" ::: "memory");
    __builtin_amdgcn_s_barrier();
    __builtin_amdgcn_sched_barrier(0);
}

__global__ __launch_bounds__(256, 1) void lstm_init_ws(unsigned int* w, int n) {
    int i = blockIdx.x * blockDim.x + threadIdx.x;
    if (i < n) __hip_atomic_store(&w[i], 0u, __ATOMIC_RELAXED, __HIP_MEMORY_SCOPE_AGENT);
}

__global__ __launch_bounds__(THREADS, 1) void lstm_persist(
    const float* __restrict__ x,
    const float* __restrict__ h0,
    const float* __restrict__ c0,
    const float* __restrict__ Wf, const float* __restrict__ Wfb,
    const float* __restrict__ Uf, const float* __restrict__ Ufb,
    const float* __restrict__ Wi, const float* __restrict__ Wib,
    const float* __restrict__ Ui, const float* __restrict__ Uib,
    const float* __restrict__ Wo, const float* __restrict__ Wob,
    const float* __restrict__ Uo, const float* __restrict__ Uob,
    const float* __restrict__ Wc, const float* __restrict__ Wcb,
    const float* __restrict__ Uc, const float* __restrict__ Ucb,
    float* out,                  // h_seq (T,B,H) | h (B,H) | c (B,H), fp32
    unsigned char* ex_fast,      // [2 slots][64 rows][128 chunks][16B], L2-scope
    unsigned char* ex_slow,      // same layout, MALL-scope (may alias ex_fast)
    unsigned int* ctrl)          // [0]=any_slow [1]=done counter
{
    __shared__ __attribute__((aligned(16))) unsigned char hfrag[17392]; // 1024 frags
    __shared__ __attribute__((aligned(16))) unsigned char xfrag[8688];  // 512 frags
    __shared__ float g_lds[8 * 320];   // gate outputs, 2-way-max banks
    __shared__ unsigned int warm_fail_lds;
    __shared__ unsigned int mode_lds;

    const int tid  = threadIdx.x;
    const int lane = tid & 63;
    const int wave = tid >> 6;            // 0..7
    const int gate = wave >> 1;           // 0:f 1:i 2:o 3:c
    const int hlf  = wave & 1;
    const int grp  = blockIdx.x & 7;      // batch group == hoped XCD id
    const int slc  = blockIdx.x >> 3;     // hid slice 0..15
    const int bb   = grp * BLK_B;
    const int hbase= slc * BLK_H;
    const int lm   = lane & 15;
    const int lq   = lane >> 4;
    const int row  = tid >> 5;            // 0..15; rows 0..7 are real
    const int seg  = tid & 31;
    const int pr   = tid & 7;             // poll: row
    const int kb   = tid >> 3;            // poll: 8-hid block 0..63

    const float* Ug  = (gate == 0) ? Uf : (gate == 1) ? Ui : (gate == 2) ? Uo : Uc;
    const float* Wg  = (gate == 0) ? Wf : (gate == 1) ? Wi : (gate == 2) ? Wo : Wc;
    const float* Wbg = (gate == 0) ? Wfb : (gate == 1) ? Wib : (gate == 2) ? Wob : Wcb;
    const float* Ubg = (gate == 0) ? Ufb : (gate == 1) ? Uib : (gate == 2) ? Uob : Ucb;
    const int ng = hbase + hlf * 16 + lm;

    // ---- register-resident bf16 weight fragments ----
    short8 ufrag[16];
#pragma unroll
    for (int ks = 0; ks < 16; ++ks) {
        const float* p = Ug + (size_t)ng * HID + ks * 32 + lq * 8;
        ufrag[ks] = pack8(*(const float4*)(p), *(const float4*)(p + 4));
    }
    short8 wfrag[8];
#pragma unroll
    for (int ks = 0; ks < 8; ++ks) {
        const float* p = Wg + (size_t)ng * IN_D + ks * 32 + lq * 8;
        wfrag[ks] = pack8(*(const float4*)(p), *(const float4*)(p + 4));
    }
    const float bias = Wbg[ng] + Ubg[ng];

    // ---- zero LDS frags (garbage M-rows must be finite, never staged) ----
    for (int i = tid; i < 17392 / 4; i += THREADS) ((unsigned int*)hfrag)[i] = 0u;
    for (int i = tid; i < 8688 / 4;  i += THREADS) ((unsigned int*)xfrag)[i] = 0u;
    if (tid == 0) { warm_fail_lds = 0u; mode_lds = 0u; }
    __syncthreads();

    // ---- cell state: thread (row<8, seg) owns c[row][hbase+seg] ----
    float c_reg = 0.f;
    if (row < 8) c_reg = c0[(size_t)(bb + row) * HID + hbase + seg];

    // ---- stage h0 (2 frags) and x0 (1 frag) for real rows ----
    if (row < 8) {
        const float* ph = h0 + (size_t)(bb + row) * HID + seg * 16;
        int f0 = (seg >> 1) * 64 + (seg & 1) * 32 + row;
        *(short8*)(hfrag + FRAG_ADDR(f0))      = pack8(*(const float4*)(ph),     *(const float4*)(ph + 4));
        *(short8*)(hfrag + FRAG_ADDR(f0 + 16)) = pack8(*(const float4*)(ph + 8), *(const float4*)(ph + 12));
        const float* px = x + (size_t)(bb + row) * IN_D + seg * 8;
        int fx = (seg >> 2) * 64 + (seg & 3) * 16 + row;
        *(short8*)(xfrag + FRAG_ADDR(fx)) = pack8(*(const float4*)(px), *(const float4*)(px + 4));
    }
    // preload x(1) into parity pair A
    float4 xa0 = {0,0,0,0}, xa1 = {0,0,0,0}, xb0 = {0,0,0,0}, xb1 = {0,0,0,0};
    if (row < 8) {
        const float* px = x + ((size_t)1 * BATCH + bb + row) * IN_D + seg * 8;
        xa0 = *(const float4*)(px); xa1 = *(const float4*)(px + 4);
    }
    __syncthreads();

    // accx = bias + x_0 @ W^T
    float4v accx0 = {bias, bias, bias, bias};
    float4v accx1 = {0.f, 0.f, 0.f, 0.f};
#pragma unroll
    for (int ks = 0; ks < 8; ++ks) {
        short8 a = *(const short8*)(xfrag + FRAG_ADDR(ks * 64 + lane));
        if (ks & 1) accx1 = __builtin_amdgcn_mfma_f32_16x16x32_bf16(a, wfrag[ks], accx1, 0, 0, 0);
        else        accx0 = __builtin_amdgcn_mfma_f32_16x16x32_bf16(a, wfrag[ks], accx0, 0, 0, 0);
    }

    float* const out_h = out + (size_t)T_STEPS * BATCH * HID;
    float* const out_c = out_h + (size_t)BATCH * HID;

    unsigned char* const fa_wr = ex_fast + (size_t)((bb + row) * CH_ROW + slc * 8 + (seg >> 2)) * 16;
    unsigned char* const sl_wr = ex_slow + (size_t)((bb + row) * CH_ROW + slc * 8 + (seg >> 2)) * 16;
    const unsigned char* const fa_rd = ex_fast + (size_t)((bb + pr) * CH_ROW + kb * 2) * 16;
    const unsigned char* const sl_rd = ex_slow + (size_t)((bb + pr) * CH_ROW + kb * 2) * 16;

    int mode = 0;   // 0 = fast(L2), 1 = slow(MALL); valid for t >= WARMUP

    auto STEP = [&](int t, float4& sx0, float4& sx1, float4& px0, float4& px1) {
        // ---- one-time placement consensus ----
        if (t == WARMUP) {
            if (tid == 0) {
                if (warm_fail_lds)
                    __hip_atomic_store(&ctrl[0], 1u, __ATOMIC_RELAXED, __HIP_MEMORY_SCOPE_AGENT);
                asm volatile("s_waitcnt vmcnt(0)" ::: "memory");
                __hip_atomic_fetch_add(&ctrl[1], 1u, __ATOMIC_RELAXED, __HIP_MEMORY_SCOPE_AGENT);
                long g = 0;
                while (__hip_atomic_load(&ctrl[1], __ATOMIC_RELAXED, __HIP_MEMORY_SCOPE_AGENT) < (unsigned)NBLK
                       && ++g < (1L << 26)) { }
                mode_lds = __hip_atomic_load(&ctrl[0], __ATOMIC_RELAXED, __HIP_MEMORY_SCOPE_AGENT);
            }
            __syncthreads();
            mode = (int)mode_lds;
        }
        const bool warm = (t < WARMUP);

        // ---- issue x(t+2) prefetch (consumed NEXT iteration: fully hidden) ----
        if (row < 8) {
            int tn = (t + 2 < T_STEPS) ? (t + 2) : (T_STEPS - 1);
            const float* px = x + ((size_t)tn * BATCH + bb + row) * IN_D + seg * 8;
            px0 = *(const float4*)(px); px1 = *(const float4*)(px + 4);
        }

        // ---- h-part MFMAs ----
        float4v acc0 = accx0, acc1 = accx1;
#pragma unroll
        for (int ks = 0; ks < 16; ++ks) {
            short8 a = *(const short8*)(hfrag + FRAG_ADDR(ks * 64 + lane));
            if (ks & 1) acc1 = __builtin_amdgcn_mfma_f32_16x16x32_bf16(a, ufrag[ks], acc1, 0, 0, 0);
            else        acc0 = __builtin_amdgcn_mfma_f32_16x16x32_bf16(a, ufrag[ks], acc0, 0, 0, 0);
        }
        float4v acc = acc0 + acc1;
#pragma unroll
        for (int r = 0; r < 4; ++r)
            g_lds[wave * 320 + lq * 80 + r * 16 + lm] = acc[r];

        // ---- stage xfrag(t+1) from parity regs (loaded last iteration) ----
        if (t + 1 < T_STEPS && row < 8) {
            int fx = (seg >> 2) * 64 + (seg & 3) * 16 + row;
            *(short8*)(xfrag + FRAG_ADDR(fx)) = pack8(sx0, sx1);
        }

        lds_barrier();   // A: g_lds + xfrag visible; hfrag reads drained

        // ---- pointwise (real rows only) ----
        float hv = 0.f;
        if (row < 8) {
            int hf2 = seg >> 4, nn = seg & 15;
            int rbase = (row >> 2) * 80 + (row & 3) * 16 + nn;
            float fpre = g_lds[(0 * 2 + hf2) * 320 + rbase];
            float ipre = g_lds[(1 * 2 + hf2) * 320 + rbase];
            float opre = g_lds[(2 * 2 + hf2) * 320 + rbase];
            float gpre = g_lds[(3 * 2 + hf2) * 320 + rbase];
            float fv = sigm(fpre), iv = sigm(ipre), ov = sigm(opre);
            float gv = tanh_(gpre);
            c_reg = fv * c_reg + iv * gv;
            hv = ov * tanh_(c_reg);
            out[((size_t)t * BATCH + bb + row) * HID + hbase + seg] = hv;
        }

        if (t + 1 < T_STEPS) {
            // ---- publish h_t chunks [4 bf16 | tag | 0] ----
            if (row < 8) {
                unsigned int bfv = f2bf(hv);
                unsigned int nb  = (unsigned int)__shfl_xor((int)bfv, 1);
                unsigned int p   = bfv | (nb << 16);
                unsigned int q   = (unsigned int)__shfl_xor((int)p, 2);
                if ((tid & 3) == 0) {
                    int4v ch; ch[0] = (int)p; ch[1] = (int)q; ch[2] = t + 1; ch[3] = 0;
                    const size_t so = (size_t)(t & 1) * SLOT_BYTES;
                    if (warm || mode == 0)
                        asm volatile("global_store_dwordx4 %0, %1, off sc0"
                                     :: "v"(fa_wr + so), "v"(ch) : "memory");
                    if (warm || mode == 1)
                        asm volatile("global_store_dwordx4 %0, %1, off sc0 sc1"
                                     :: "v"(sl_wr + so), "v"(ch) : "memory");
                }
            }

            // ---- accx for t+1 (overlaps store flight) ----
            accx0 = (float4v){bias, bias, bias, bias};
            accx1 = (float4v){0.f, 0.f, 0.f, 0.f};
#pragma unroll
            for (int ks = 0; ks < 8; ++ks) {
                short8 a = *(const short8*)(xfrag + FRAG_ADDR(ks * 64 + lane));
                if (ks & 1) accx1 = __builtin_amdgcn_mfma_f32_16x16x32_bf16(a, wfrag[ks], accx1, 0, 0, 0);
                else        accx0 = __builtin_amdgcn_mfma_f32_16x16x32_bf16(a, wfrag[ks], accx0, 0, 0, 0);
            }

            // ---- poll h_t (2 chunks = 32B per thread) ----
            const int want = t + 1;
            const size_t so = (size_t)(t & 1) * SLOT_BYTES;
            int4v e0, e1;
            bool got = false;
            if (warm || mode == 0) {
                const unsigned char* pb = fa_rd + so;
                long cap = warm ? (long)FAST_CAP : (1L << 24);
                for (long it = 0; it < cap; ++it) {
                    asm volatile(
                        "global_load_dwordx4 %0, %2, off sc0\n\t"
                        "global_load_dwordx4 %1, %2, off offset:16 sc0\n\t"
                        "s_waitcnt vmcnt(0)"
                        : "=&v"(e0), "=&v"(e1) : "v"(pb) : "memory");
                    if ((e0[2] == want) & (e1[2] == want)) { got = true; break; }
                }
            }
            if (!got) {
                if (warm) warm_fail_lds = 1u;   // benign race
                const unsigned char* pb = sl_rd + so;
                long guard = 0;
                for (;;) {
                    asm volatile(
                        "global_load_dwordx4 %0, %2, off sc0 sc1\n\t"
                        "global_load_dwordx4 %1, %2, off offset:16 sc0 sc1\n\t"
                        "s_waitcnt vmcnt(0)"
                        : "=&v"(e0), "=&v"(e1) : "v"(pb) : "memory");
                    if ((e0[2] == want) & (e1[2] == want)) break;
                    if (++guard > (1L << 24)) break;   // fail visibly, not hang
                }
            }
            // ---- unpack straight into hfrag (bf16) ----
            int f0 = (kb >> 2) * 64 + (kb & 3) * 16 + pr;
            *(int4v*)(hfrag + FRAG_ADDR(f0)) = (int4v){e0[0], e0[1], e1[0], e1[1]};

            lds_barrier();   // C: hfrag ready for next iteration
        } else {
            if (row < 8) {
                out_h[(size_t)(bb + row) * HID + hbase + seg] = hv;
                out_c[(size_t)(bb + row) * HID + hbase + seg] = c_reg;
            }
        }
    };

    for (int t = 0; t < T_STEPS; t += 2) {
        STEP(t,     xa0, xa1, xb0, xb1);
        STEP(t + 1, xb0, xb1, xa0, xa1);
    }
}

extern "C" void kernel_launch(void* const* d_in, const int* in_sizes, int n_in,
                              void* d_out, int out_size, void* d_ws, size_t ws_size,
                              hipStream_t stream) {
    (void)in_sizes; (void)n_in; (void)out_size;
    const float* x   = (const float*)d_in[0];
    const float* h0  = (const float*)d_in[1];
    const float* c0  = (const float*)d_in[2];
    const float* Wf  = (const float*)d_in[3];
    const float* Wfb = (const float*)d_in[4];
    const float* Uf  = (const float*)d_in[5];
    const float* Ufb = (const float*)d_in[6];
    const float* Wi  = (const float*)d_in[7];
    const float* Wib = (const float*)d_in[8];
    const float* Ui  = (const float*)d_in[9];
    const float* Uib = (const float*)d_in[10];
    const float* Wo  = (const float*)d_in[11];
    const float* Wob = (const float*)d_in[12];
    const float* Uo  = (const float*)d_in[13];
    const float* Uob = (const float*)d_in[14];
    const float* Wc  = (const float*)d_in[15];
    const float* Wcb = (const float*)d_in[16];
    const float* Uc  = (const float*)d_in[17];
    const float* Ucb = (const float*)d_in[18];

    unsigned char* base = (unsigned char*)d_ws;
    unsigned char* ex_fast = base;
    unsigned char* ex_slow;
    size_t used;
    if (ws_size >= 4 * (size_t)SLOT_BYTES + 64) {
        ex_slow = base + 2 * (size_t)SLOT_BYTES;
        used = 4 * (size_t)SLOT_BYTES + 64;
    } else {
        ex_slow = base;                       // alias: identical payload+tag, safe
        used = 2 * (size_t)SLOT_BYTES + 64;
    }
    unsigned int* ctrl = (unsigned int*)(base + used - 64);

    const int nzero = (int)(used / 4);
    lstm_init_ws<<<(nzero + 255) / 256, 256, 0, stream>>>((unsigned int*)base, nzero);
    lstm_persist<<<NBLK, THREADS, 0, stream>>>(
        x, h0, c0,
        Wf, Wfb, Uf, Ufb, Wi, Wib, Ui, Uib,
        Wo, Wob, Uo, Uob, Wc, Wcb, Uc, Ucb,
        (float*)d_out, ex_fast, ex_slow, ctrl);
}

// Round 4
// 1532.277 us; speedup vs baseline: 1.1922x; 1.1922x over previous
//
#include <hip/hip_runtime.h>

// LSTM: SEQ=512, B=64, IN=256, H=512, fp32 in/out; bf16 MFMA compute.
// Round-0 proven topology: 4 batch-groups x 16 H-slice blocks (32 hid x 4
// gates), persistent, 512 steps, M=16 full MFMA.
//
// Exchange protocol (v4):
//  - payload: bf16 h, 2-slot buffer hx[slot][grp][row16][512], write-through
//    (sc0 sc1) stores; consumer bulk-reads 32B/thread with coherent loads.
//  - notification: 16 INDEPENDENT per-producer flag dwords per group
//    (no atomic RMW chain), monotonic tag t+1, consumer polls all 16 with
//    one 64B burst and compares >= (handles 1-step producer skew).
//  - producer order: h stores -> per-wave vmcnt(0) -> s_barrier -> tid0 flag.
//  - x(t+2) HBM prefetch issued AFTER the flag store: its ~900cy latency no
//    longer sits inside the ack drain (round-0 bug).
//  - slot reuse safe: producer rewrites slot p at t+2 only after observing
//    all tags t+2, each published strictly after that peer's slot-p reads
//    completed.
// In-loop barriers are LDS-only or raw (no implicit vmcnt(0) drains).
// out h_seq = plain cached stores (off critical path; L2 flushed at kernel end).

#define T_STEPS 512
#define BATCH   64
#define IN_D    256
#define HID     512
#define NGROUP  4
#define NSLICE  16
#define BLK_B   16
#define BLK_H   32
#define THREADS 512
#define ROW_BYTES  1024                        // 512 bf16
#define GRP_BYTES  (BLK_B * ROW_BYTES)         // 16 KB
#define SLOT_BYTES (NGROUP * GRP_BYTES)        // 64 KB
#define FLAGS_OFF  (2 * SLOT_BYTES)            // flags after 128 KB of slots
#define NFLAGS     (NGROUP * NSLICE)           // 64 dwords

using short8  = __attribute__((ext_vector_type(8))) short;
using int4v   = __attribute__((ext_vector_type(4))) int;
using float4v = __attribute__((ext_vector_type(4))) float;

#define FRAG_ADDR(f) (((f) << 4) + (((f) >> 4) << 4))   // 16B frag + 16B pad / 16 frags

__device__ __forceinline__ unsigned short f2bf(float f) {
    union { float f; unsigned int i; } v; v.f = f;
    unsigned int r = v.i + 0x7fff + ((v.i >> 16) & 1);
    return (unsigned short)(r >> 16);
}
__device__ __forceinline__ short8 pack8(float4 a, float4 b) {
    short8 s;
    s[0]=(short)f2bf(a.x); s[1]=(short)f2bf(a.y); s[2]=(short)f2bf(a.z); s[3]=(short)f2bf(a.w);
    s[4]=(short)f2bf(b.x); s[5]=(short)f2bf(b.y); s[6]=(short)f2bf(b.z); s[7]=(short)f2bf(b.w);
    return s;
}
__device__ __forceinline__ float sigm(float v) { return 1.0f / (1.0f + __expf(-v)); }
__device__ __forceinline__ float tanh_(float v) { return 2.0f / (1.0f + __expf(-2.0f * v)) - 1.0f; }

// LDS-visibility barrier WITHOUT the vmcnt(0) drain of __syncthreads.
__device__ __forceinline__ void lds_barrier() {
    asm volatile("s_waitcnt lgkmcnt(0)" ::: "memory");
    __builtin_amdgcn_s_barrier();
    __builtin_amdgcn_sched_barrier(0);
}

__global__ __launch_bounds__(256, 1) void lstm_init_ws(unsigned int* w, int n) {
    int i = blockIdx.x * blockDim.x + threadIdx.x;
    if (i < n) __hip_atomic_store(&w[i], 0u, __ATOMIC_RELAXED, __HIP_MEMORY_SCOPE_AGENT);
}

__global__ __launch_bounds__(THREADS, 1) void lstm_persist(
    const float* __restrict__ x,
    const float* __restrict__ h0,
    const float* __restrict__ c0,
    const float* __restrict__ Wf, const float* __restrict__ Wfb,
    const float* __restrict__ Uf, const float* __restrict__ Ufb,
    const float* __restrict__ Wi, const float* __restrict__ Wib,
    const float* __restrict__ Ui, const float* __restrict__ Uib,
    const float* __restrict__ Wo, const float* __restrict__ Wob,
    const float* __restrict__ Uo, const float* __restrict__ Uob,
    const float* __restrict__ Wc, const float* __restrict__ Wcb,
    const float* __restrict__ Uc, const float* __restrict__ Ucb,
    float* out,                  // h_seq (T,B,H) | h (B,H) | c (B,H), fp32
    unsigned char* exch)         // [2][NGROUP][16][1KB] bf16 slots | 64 flags
{
    __shared__ __attribute__((aligned(16))) unsigned char hfrag[17392]; // 1024 frags
    __shared__ __attribute__((aligned(16))) unsigned char xfrag[8688];  // 512 frags
    __shared__ float g_lds[8 * 256];                                    // gate outputs

    const int tid  = threadIdx.x;
    const int lane = tid & 63;
    const int wave = tid >> 6;            // 0..7
    const int gate = wave >> 1;           // 0:f 1:i 2:o 3:c
    const int hlf  = wave & 1;            // 16-hid half of the 32
    const int grp  = blockIdx.x & 3;      // batch group
    const int slc  = blockIdx.x >> 2;     // hid slice
    const int bb   = grp * BLK_B;
    const int hbase= slc * BLK_H;
    const int lm   = lane & 15;
    const int lq   = lane >> 4;
    const int row  = tid >> 5;            // 0..15 (batch within group)
    const int seg  = tid & 31;            // 0..31

    const float* Ug  = (gate == 0) ? Uf : (gate == 1) ? Ui : (gate == 2) ? Uo : Uc;
    const float* Wg  = (gate == 0) ? Wf : (gate == 1) ? Wi : (gate == 2) ? Wo : Wc;
    const float* Wbg = (gate == 0) ? Wfb : (gate == 1) ? Wib : (gate == 2) ? Wob : Wcb;
    const float* Ubg = (gate == 0) ? Ufb : (gate == 1) ? Uib : (gate == 2) ? Uob : Ucb;
    const int ng = hbase + hlf * 16 + lm;   // lane's gate-output row (B-op n)

    // ---- register-resident bf16 weight fragments ----
    short8 ufrag[16];
#pragma unroll
    for (int ks = 0; ks < 16; ++ks) {
        const float* p = Ug + (size_t)ng * HID + ks * 32 + lq * 8;
        ufrag[ks] = pack8(*(const float4*)(p), *(const float4*)(p + 4));
    }
    short8 wfrag[8];
#pragma unroll
    for (int ks = 0; ks < 8; ++ks) {
        const float* p = Wg + (size_t)ng * IN_D + ks * 32 + lq * 8;
        wfrag[ks] = pack8(*(const float4*)(p), *(const float4*)(p + 4));
    }
    const float bias = Wbg[ng] + Ubg[ng];

    // ---- cell state in registers: thread (row,seg) owns c[row][hbase+seg] ----
    float c_reg = c0[(size_t)(bb + row) * HID + hbase + seg];

    // ---- stage h0 (2 frags/thread) and x0 (1 frag/thread) ----
    {
        const float* ph = h0 + (size_t)(bb + row) * HID + seg * 16;
        int f0 = (seg >> 1) * 64 + (seg & 1) * 32 + row;
        *(short8*)(hfrag + FRAG_ADDR(f0))      = pack8(*(const float4*)(ph),     *(const float4*)(ph + 4));
        *(short8*)(hfrag + FRAG_ADDR(f0 + 16)) = pack8(*(const float4*)(ph + 8), *(const float4*)(ph + 12));

        const float* px = x + (size_t)(bb + row) * IN_D + seg * 8;
        int fx = (seg >> 2) * 64 + (seg & 3) * 16 + row;
        *(short8*)(xfrag + FRAG_ADDR(fx)) = pack8(*(const float4*)(px), *(const float4*)(px + 4));
    }
    // preload x(1) into parity pair A
    float4 xa0, xa1, xb0 = {0,0,0,0}, xb1 = {0,0,0,0};
    {
        const float* px = x + ((size_t)1 * BATCH + bb + row) * IN_D + seg * 8;
        xa0 = *(const float4*)(px); xa1 = *(const float4*)(px + 4);
    }
    __syncthreads();

    // accx = bias + x_0 @ W^T
    float4v accx0 = {bias, bias, bias, bias};
    float4v accx1 = {0.f, 0.f, 0.f, 0.f};
#pragma unroll
    for (int ks = 0; ks < 8; ++ks) {
        short8 a = *(const short8*)(xfrag + FRAG_ADDR(ks * 64 + lane));
        if (ks & 1) accx1 = __builtin_amdgcn_mfma_f32_16x16x32_bf16(a, wfrag[ks], accx1, 0, 0, 0);
        else        accx0 = __builtin_amdgcn_mfma_f32_16x16x32_bf16(a, wfrag[ks], accx0, 0, 0, 0);
    }

    float* const out_h = out + (size_t)T_STEPS * BATCH * HID;
    float* const out_c = out_h + (size_t)BATCH * HID;

    // exchange addresses
    unsigned char* const ex_wr = exch + (size_t)grp * GRP_BYTES
                               + (size_t)row * ROW_BYTES + (size_t)(hbase + seg) * 2;
    const unsigned char* const ex_rd = exch + (size_t)grp * GRP_BYTES + (size_t)tid * 32;
    unsigned int* const flg = (unsigned int*)(exch + FLAGS_OFF) + grp * NSLICE;
    unsigned int* const flg_wr = flg + slc;

    auto STEP = [&](int t, float4& sx0, float4& sx1, float4& px0, float4& px1) {
        // ---- h-part MFMAs on top of accx ----
        float4v acc0 = accx0, acc1 = accx1;
#pragma unroll
        for (int ks = 0; ks < 16; ++ks) {
            short8 a = *(const short8*)(hfrag + FRAG_ADDR(ks * 64 + lane));
            if (ks & 1) acc1 = __builtin_amdgcn_mfma_f32_16x16x32_bf16(a, ufrag[ks], acc1, 0, 0, 0);
            else        acc0 = __builtin_amdgcn_mfma_f32_16x16x32_bf16(a, ufrag[ks], acc0, 0, 0, 0);
        }
        float4v acc = acc0 + acc1;
#pragma unroll
        for (int r = 0; r < 4; ++r)
            g_lds[wave * 256 + (lq * 4 + r) * 16 + lm] = acc[r];

        // ---- stage xfrag(t+1) from parity regs (loaded LAST iteration) ----
        if (t + 1 < T_STEPS) {
            int fx = (seg >> 2) * 64 + (seg & 3) * 16 + row;
            *(short8*)(xfrag + FRAG_ADDR(fx)) = pack8(sx0, sx1);
        }

        lds_barrier();   // A: g_lds + xfrag visible; hfrag MFMA reads drained

        // ---- pointwise (fp32, c in register) ----
        float hv;
        {
            int hf2 = seg >> 4, nn = seg & 15;
            float fpre = g_lds[(0 * 2 + hf2) * 256 + row * 16 + nn];
            float ipre = g_lds[(1 * 2 + hf2) * 256 + row * 16 + nn];
            float opre = g_lds[(2 * 2 + hf2) * 256 + row * 16 + nn];
            float gpre = g_lds[(3 * 2 + hf2) * 256 + row * 16 + nn];
            float fv = sigm(fpre), iv = sigm(ipre), ov = sigm(opre);
            float gv = tanh_(gpre);
            c_reg = fv * c_reg + iv * gv;
            hv = ov * tanh_(c_reg);
        }
        out[((size_t)t * BATCH + bb + row) * HID + hbase + seg] = hv;  // plain cached

        if (t + 1 < T_STEPS) {
            // ---- publish h_t: bf16 pair per even thread, write-through ----
            {
                unsigned int bfv = f2bf(hv);
                unsigned int nb  = (unsigned int)__shfl_xor((int)bfv, 1);
                if ((tid & 1) == 0) {
                    unsigned int pw = bfv | (nb << 16);
                    const unsigned char* pa = ex_wr + (size_t)(t & 1) * SLOT_BYTES;
                    asm volatile("global_store_dword %0, %1, off sc0 sc1"
                                 :: "v"(pa), "v"(pw) : "memory");
                }
            }
            asm volatile("s_waitcnt vmcnt(0)" ::: "memory");  // per-wave store ack
            __builtin_amdgcn_s_barrier();                     // all waves acked
            __builtin_amdgcn_sched_barrier(0);
            if (tid == 0) {
                asm volatile("global_store_dword %0, %1, off sc0 sc1"
                             :: "v"(flg_wr), "v"((unsigned int)(t + 1)) : "memory");
            }

            // ---- x(t+2) prefetch NOW (outside the ack drain) ----
            {
                int tn = (t + 2 < T_STEPS) ? (t + 2) : (T_STEPS - 1);
                const float* px = x + ((size_t)tn * BATCH + bb + row) * IN_D + seg * 8;
                px0 = *(const float4*)(px); px1 = *(const float4*)(px + 4);
            }

            // ---- accx for t+1 (overlaps flag propagation) ----
            accx0 = (float4v){bias, bias, bias, bias};
            accx1 = (float4v){0.f, 0.f, 0.f, 0.f};
#pragma unroll
            for (int ks = 0; ks < 8; ++ks) {
                short8 a = *(const short8*)(xfrag + FRAG_ADDR(ks * 64 + lane));
                if (ks & 1) accx1 = __builtin_amdgcn_mfma_f32_16x16x32_bf16(a, wfrag[ks], accx1, 0, 0, 0);
                else        accx0 = __builtin_amdgcn_mfma_f32_16x16x32_bf16(a, wfrag[ks], accx0, 0, 0, 0);
            }

            // ---- tid0 polls 16 independent flags (64B burst), tag >= t+1 ----
            if (tid == 0) {
                const unsigned int want = (unsigned int)(t + 1);
                int4v q0, q1, q2, q3;
                long guard = 0;
                for (;;) {
                    asm volatile(
                        "global_load_dwordx4 %0, %4, off sc0 sc1\n\t"
                        "global_load_dwordx4 %1, %4, off offset:16 sc0 sc1\n\t"
                        "global_load_dwordx4 %2, %4, off offset:32 sc0 sc1\n\t"
                        "global_load_dwordx4 %3, %4, off offset:48 sc0 sc1\n\t"
                        "s_waitcnt vmcnt(0)"
                        : "=&v"(q0), "=&v"(q1), "=&v"(q2), "=&v"(q3)
                        : "v"(flg) : "memory");
                    bool ok = true;
#pragma unroll
                    for (int j = 0; j < 4; ++j) {
                        ok &= ((unsigned int)q0[j] >= want);
                        ok &= ((unsigned int)q1[j] >= want);
                        ok &= ((unsigned int)q2[j] >= want);
                        ok &= ((unsigned int)q3[j] >= want);
                    }
                    if (ok) break;
                    if (++guard > (1L << 22)) break;   // fail visibly, not hang
                }
            }
            __builtin_amdgcn_s_barrier();   // B: h_t certified for whole block
            __builtin_amdgcn_sched_barrier(0);

            // ---- bulk coherent load: 32B/thread of bf16 h, straight to LDS ----
            {
                const unsigned char* pb = ex_rd + (size_t)(t & 1) * SLOT_BYTES;
                int4v e0, e1;
                asm volatile(
                    "global_load_dwordx4 %0, %2, off sc0 sc1\n\t"
                    "global_load_dwordx4 %1, %2, off offset:16 sc0 sc1\n\t"
                    "s_waitcnt vmcnt(0)"
                    : "=&v"(e0), "=&v"(e1) : "v"(pb) : "memory");
                int f0 = (seg >> 1) * 64 + (seg & 1) * 32 + row;
                *(int4v*)(hfrag + FRAG_ADDR(f0))      = e0;
                *(int4v*)(hfrag + FRAG_ADDR(f0 + 16)) = e1;
            }
            lds_barrier();   // C: hfrag ready for next iteration's MFMAs
        } else {
            out_h[(size_t)(bb + row) * HID + hbase + seg] = hv;
            out_c[(size_t)(bb + row) * HID + hbase + seg] = c_reg;
        }
    };

    for (int t = 0; t < T_STEPS; t += 2) {
        STEP(t,     xa0, xa1, xb0, xb1);
        STEP(t + 1, xb0, xb1, xa0, xa1);
    }
}

extern "C" void kernel_launch(void* const* d_in, const int* in_sizes, int n_in,
                              void* d_out, int out_size, void* d_ws, size_t ws_size,
                              hipStream_t stream) {
    (void)in_sizes; (void)n_in; (void)out_size; (void)ws_size;
    const float* x   = (const float*)d_in[0];
    const float* h0  = (const float*)d_in[1];
    const float* c0  = (const float*)d_in[2];
    const float* Wf  = (const float*)d_in[3];
    const float* Wfb = (const float*)d_in[4];
    const float* Uf  = (const float*)d_in[5];
    const float* Ufb = (const float*)d_in[6];
    const float* Wi  = (const float*)d_in[7];
    const float* Wib = (const float*)d_in[8];
    const float* Ui  = (const float*)d_in[9];
    const float* Uib = (const float*)d_in[10];
    const float* Wo  = (const float*)d_in[11];
    const float* Wob = (const float*)d_in[12];
    const float* Uo  = (const float*)d_in[13];
    const float* Uob = (const float*)d_in[14];
    const float* Wc  = (const float*)d_in[15];
    const float* Wcb = (const float*)d_in[16];
    const float* Uc  = (const float*)d_in[17];
    const float* Ucb = (const float*)d_in[18];

    unsigned char* exch = (unsigned char*)d_ws;
    // zero only the flag words (tags are monotonic within a run)
    unsigned int* flags = (unsigned int*)(exch + FLAGS_OFF);
    lstm_init_ws<<<1, 256, 0, stream>>>(flags, NFLAGS);
    lstm_persist<<<NGROUP * NSLICE, THREADS, 0, stream>>>(
        x, h0, c0,
        Wf, Wfb, Uf, Ufb, Wi, Wib, Ui, Uib,
        Wo, Wob, Uo, Uob, Wc, Wcb, Uc, Ucb,
        (float*)d_out, exch);
}